// Round 1
// baseline (361.769 us; speedup 1.0000x reference)
//
#include <hip/hip_runtime.h>

#define EBLK 64
#define NWAVES 3
#define NTHREADS 192
#define STRIDE 168   // padded feature stride in bf16 elems (row = 336 B, 16B-aligned)

using f32x4 = __attribute__((ext_vector_type(4))) float;
using bf8   = __attribute__((ext_vector_type(8))) short;

__device__ __forceinline__ ushort f2bf(float f) {
    union { float f; unsigned u; } c{f};
    unsigned u = c.u;
    unsigned r = (u + 0x7fffu + ((u >> 16) & 1u)) >> 16;   // RTNE
    return (ushort)r;
}
__device__ __forceinline__ float bf2f(ushort s) {
    union { unsigned u; float f; } c{((unsigned)s) << 16};
    return c.f;
}

// ---------------- weight repack: f32 [K][N] -> bf16 A-fragment lines ----------------
// A-fragment (mfma_f32_16x16x32_bf16): lane l holds A[m = l&15][k = (l>>4)*8 + j], j=0..7
// layout: frag[((nt*KS + ks)*64 + l)*8 + j]; m = nt*16 + (l&15); k = ks*32 + (l>>4)*8 + j
// start layer: KS=1 (K=32); hidden: KS=5 (K=144 zero-padded to 160)
__global__ void repack_kernel(const float* __restrict__ Wstart,
                              const float* __restrict__ Wh0,
                              const float* __restrict__ Wh1,
                              const float* __restrict__ Wh2,
                              ushort* __restrict__ frag) {
    int i = blockIdx.x * blockDim.x + threadIdx.x;
    if (i < 4608) {                       // start: 9 nt * 1 ks * 64 * 8
        int j = i & 7, l = (i >> 3) & 63, nt = i >> 9;
        int k = ((l >> 4) << 3) + j;
        int n = nt * 16 + (l & 15);
        frag[i] = f2bf(Wstart[k * 144 + n]);
    } else if (i < 73728) {               // hidden: 3 * (9 nt * 5 ks * 64 * 8)
        int r = i - 4608;
        int h = r / 23040; r %= 23040;
        const float* W = (h == 0) ? Wh0 : ((h == 1) ? Wh1 : Wh2);
        int j = r & 7, l = (r >> 3) & 63, rem = r >> 9;
        int ks = rem % 5, nt = rem / 5;
        int k = ks * 32 + ((l >> 4) << 3) + j;
        int n = nt * 16 + (l & 15);
        float v = (k < 144) ? W[k * 144 + n] : 0.0f;
        frag[i] = f2bf(v);
    }
}

// ---------------- fused MLP layer: dst = relu(bias + W^T * src^T) ----------------
// C tile: col (l&15) = edge, row ((l>>4)*4+r) = out-feature  [HW-verified layout]
// B frag (X): lane l reads 8 contiguous feats of edge (l&15) -> ds_read_b128
template<int KS>
__device__ __forceinline__ void layer(const ushort* __restrict__ wfrag,
                                      const float* __restrict__ bias,
                                      const ushort (*src)[STRIDE],
                                      ushort (*dst)[STRIDE],
                                      int wave, int lane) {
    const int grp = lane >> 4, er = lane & 15;
    bf8 xf[4][KS];
    #pragma unroll
    for (int t = 0; t < 4; t++)
        #pragma unroll
        for (int k = 0; k < KS; k++)
            xf[t][k] = *(const bf8*)&src[t * 16 + er][k * 32 + grp * 8];

    #pragma unroll
    for (int ni = 0; ni < 3; ni++) {
        const int nt = wave * 3 + ni;
        f32x4 bv;
        {
            float4 b4 = *(const float4*)&bias[nt * 16 + grp * 4];
            bv[0] = b4.x; bv[1] = b4.y; bv[2] = b4.z; bv[3] = b4.w;
        }
        f32x4 acc0 = bv, acc1 = bv, acc2 = bv, acc3 = bv;
        #pragma unroll
        for (int k = 0; k < KS; k++) {
            bf8 wf = *(const bf8*)&wfrag[((((nt * KS + k) << 6) + lane) << 3)];
            acc0 = __builtin_amdgcn_mfma_f32_16x16x32_bf16(wf, xf[0][k], acc0, 0, 0, 0);
            acc1 = __builtin_amdgcn_mfma_f32_16x16x32_bf16(wf, xf[1][k], acc1, 0, 0, 0);
            acc2 = __builtin_amdgcn_mfma_f32_16x16x32_bf16(wf, xf[2][k], acc2, 0, 0, 0);
            acc3 = __builtin_amdgcn_mfma_f32_16x16x32_bf16(wf, xf[3][k], acc3, 0, 0, 0);
        }
        f32x4 accs[4] = {acc0, acc1, acc2, acc3};
        #pragma unroll
        for (int t = 0; t < 4; t++) {
            short4 o;
            o.x = (short)f2bf(fmaxf(accs[t][0], 0.0f));
            o.y = (short)f2bf(fmaxf(accs[t][1], 0.0f));
            o.z = (short)f2bf(fmaxf(accs[t][2], 0.0f));
            o.w = (short)f2bf(fmaxf(accs[t][3], 0.0f));
            *(short4*)&dst[t * 16 + er][nt * 16 + grp * 4] = o;
        }
    }
}

__global__ __launch_bounds__(NTHREADS)
void mlp_kernel(const float* __restrict__ score,
                const int* __restrict__ label_idx,
                const float* __restrict__ b_start,
                const float* __restrict__ b_h0,
                const float* __restrict__ b_h1,
                const float* __restrict__ b_h2,
                const float* __restrict__ W_end,
                const float* __restrict__ b_end,
                const ushort* __restrict__ frag,
                float* __restrict__ out) {
    __shared__ ushort act[2][EBLK][STRIDE];
    const int tid = threadIdx.x;
    const int lane = tid & 63;
    const int wave = tid >> 6;

    // zero the K-pad region (feats 144..159) of both buffers, written only here
    for (int i = tid; i < 2 * EBLK * 16; i += NTHREADS) {
        int b = i >> 10, e = (i >> 4) & 63, f = i & 15;
        act[b][e][144 + f] = 0;
    }
    // gather: act0[e][j] = bf16(score[label_idx[e][j]])
    const long base = (long)blockIdx.x * (EBLK * 32);
    for (int i = tid; i < EBLK * 32; i += NTHREADS) {
        int idx = label_idx[base + i];
        act[0][i >> 5][i & 31] = f2bf(score[idx]);
    }
    __syncthreads();
    layer<1>(frag,                 b_start, act[0], act[1], wave, lane);
    __syncthreads();
    layer<5>(frag + 4608,          b_h0,    act[1], act[0], wave, lane);
    __syncthreads();
    layer<5>(frag + 4608 + 23040,  b_h1,    act[0], act[1], wave, lane);
    __syncthreads();
    layer<5>(frag + 4608 + 46080,  b_h2,    act[1], act[0], wave, lane);
    __syncthreads();
    // end layer: out[e] = dot(x[e], W_end) + b_end   (W_end reads are wave-uniform -> s_load)
    if (tid < EBLK) {
        float s = b_end[0];
        const ushort* x = act[0][tid];
        #pragma unroll
        for (int c = 0; c < 18; c++) {
            bf8 xv = *(const bf8*)&x[c * 8];
            #pragma unroll
            for (int q = 0; q < 8; q++)
                s += bf2f((ushort)xv[q]) * W_end[c * 8 + q];
        }
        out[blockIdx.x * EBLK + tid] = s;
    }
}

extern "C" void kernel_launch(void* const* d_in, const int* in_sizes, int n_in,
                              void* d_out, int out_size, void* d_ws, size_t ws_size,
                              hipStream_t stream) {
    const float* score   = (const float*)d_in[0];
    const int*   lidx    = (const int*)  d_in[1];
    const float* W_start = (const float*)d_in[2];
    const float* b_start = (const float*)d_in[3];
    const float* W_h0    = (const float*)d_in[4];
    const float* b_h0    = (const float*)d_in[5];
    const float* W_h1    = (const float*)d_in[6];
    const float* b_h1    = (const float*)d_in[7];
    const float* W_h2    = (const float*)d_in[8];
    const float* b_h2    = (const float*)d_in[9];
    const float* W_end   = (const float*)d_in[10];
    const float* b_end   = (const float*)d_in[11];
    float* out = (float*)d_out;
    ushort* frag = (ushort*)d_ws;   // 73728 bf16 = 147456 B of repacked weights

    repack_kernel<<<288, 256, 0, stream>>>(W_start, W_h0, W_h1, W_h2, frag);

    const int nblocks = 1000000 / EBLK;   // exact
    mlp_kernel<<<nblocks, NTHREADS, 0, stream>>>(score, lidx, b_start, b_h0, b_h1, b_h2,
                                                 W_end, b_end, frag, out);
}

// Round 3
// 325.948 us; speedup vs baseline: 1.1099x; 1.1099x over previous
//
#include <hip/hip_runtime.h>

#define EBLK 64
#define NTHREADS 192
#define STRIDE 168   // padded feature stride in bf16 elems (row = 336 B, 16B-aligned)

using f32x4 = __attribute__((ext_vector_type(4))) float;
using bf8   = __attribute__((ext_vector_type(8))) short;

__device__ __forceinline__ ushort f2bf(float f) {
    union { float f; unsigned u; } c{f};
    unsigned u = c.u;
    return (ushort)((u + 0x7fffu + ((u >> 16) & 1u)) >> 16);   // RTNE
}

__device__ __forceinline__ unsigned cvt_pk_bf16(float lo, float hi) {
    unsigned r;
    asm("v_cvt_pk_bf16_f32 %0, %1, %2" : "=v"(r) : "v"(lo), "v"(hi));
    return r;
}

// ---------------- weight repack: f32 [K][N] -> bf16 A-fragment lines ----------------
// A-fragment (mfma_f32_16x16x32_bf16): lane l holds A[m = l&15][k = (l>>4)*8 + j], j=0..7
// layout: frag[((nt*KS + ks)*64 + l)*8 + j]; m = nt*16 + (l&15); k = ks*32 + (l>>4)*8 + j
__global__ void repack_kernel(const float* __restrict__ Wstart,
                              const float* __restrict__ Wh0,
                              const float* __restrict__ Wh1,
                              const float* __restrict__ Wh2,
                              ushort* __restrict__ frag) {
    int i = blockIdx.x * blockDim.x + threadIdx.x;
    if (i < 4608) {                       // start: 9 nt * 1 ks * 64 * 8
        int j = i & 7, l = (i >> 3) & 63, nt = i >> 9;
        int k = ((l >> 4) << 3) + j;
        int n = nt * 16 + (l & 15);
        frag[i] = f2bf(Wstart[k * 144 + n]);
    } else if (i < 73728) {               // hidden: 3 * (9 nt * 5 ks * 64 * 8)
        int r = i - 4608;
        int h = r / 23040; r %= 23040;
        const float* W = (h == 0) ? Wh0 : ((h == 1) ? Wh1 : Wh2);
        int j = r & 7, l = (r >> 3) & 63, rem = r >> 9;
        int ks = rem % 5, nt = rem / 5;
        int k = ks * 32 + ((l >> 4) << 3) + j;
        int n = nt * 16 + (l & 15);
        float v = (k < 144) ? W[k * 144 + n] : 0.0f;
        frag[i] = f2bf(v);
    }
}

// ---------------- fused MLP layer, IN-PLACE: act = relu(bias + W^T * act^T) ----------------
// C tile: col (l&15) = edge-in-tile, row ((l>>4)*4+r) = out-feature  [HW-verified layout]
// Each wave reads ALL its B-input into regs first; barrier; then writes its 3 nt slices.
template<int KS, bool FINAL>
__device__ __forceinline__ void layer_op(const ushort* __restrict__ wfrag,
                                         const float* __restrict__ bias,
                                         ushort (*act)[STRIDE],
                                         const float* __restrict__ W_end,
                                         float* __restrict__ pdot,
                                         int wave, int lane) {
    const int grp = lane >> 4, er = lane & 15;
    bf8 xf[4][KS];
    #pragma unroll
    for (int t = 0; t < 4; t++)
        #pragma unroll
        for (int k = 0; k < KS; k++)
            xf[t][k] = *(const bf8*)&act[t * 16 + er][k * 32 + grp * 8];
    __syncthreads();   // all waves' reads complete before any in-place write

    float part[4] = {0.f, 0.f, 0.f, 0.f};
    #pragma unroll
    for (int ni = 0; ni < 3; ni++) {
        const int nt = wave * 3 + ni;
        f32x4 bv;
        {
            float4 b4 = *(const float4*)&bias[nt * 16 + grp * 4];
            bv[0] = b4.x; bv[1] = b4.y; bv[2] = b4.z; bv[3] = b4.w;
        }
        f32x4 acc[4] = {bv, bv, bv, bv};
        #pragma unroll
        for (int k = 0; k < KS; k++) {
            bf8 wf = *(const bf8*)&wfrag[(((nt * KS + k) << 6) + lane) << 3];
            #pragma unroll
            for (int t = 0; t < 4; t++)
                acc[t] = __builtin_amdgcn_mfma_f32_16x16x32_bf16(wf, xf[t][k], acc[t], 0, 0, 0);
        }
        if constexpr (FINAL) {
            // fold x @ W_end into the epilogue, in f32 (no bf16 round-trip)
            float4 wv = *(const float4*)&W_end[nt * 16 + grp * 4];
            #pragma unroll
            for (int t = 0; t < 4; t++) {
                part[t] += fmaxf(acc[t][0], 0.f) * wv.x;
                part[t] += fmaxf(acc[t][1], 0.f) * wv.y;
                part[t] += fmaxf(acc[t][2], 0.f) * wv.z;
                part[t] += fmaxf(acc[t][3], 0.f) * wv.w;
            }
        } else {
            #pragma unroll
            for (int t = 0; t < 4; t++) {
                uint2 o;
                o.x = cvt_pk_bf16(fmaxf(acc[t][0], 0.f), fmaxf(acc[t][1], 0.f));
                o.y = cvt_pk_bf16(fmaxf(acc[t][2], 0.f), fmaxf(acc[t][3], 0.f));
                *(uint2*)&act[t * 16 + er][nt * 16 + grp * 4] = o;
            }
        }
    }
    if constexpr (FINAL) {
        #pragma unroll
        for (int t = 0; t < 4; t++) {
            part[t] += __shfl_xor(part[t], 16, 64);   // reduce across the 4 lane-groups
            part[t] += __shfl_xor(part[t], 32, 64);
        }
        if (lane < 16) {
            #pragma unroll
            for (int t = 0; t < 4; t++)
                pdot[wave * EBLK + t * 16 + lane] = part[t];
        }
    }
    __syncthreads();
}

__global__ __launch_bounds__(NTHREADS, 4)
void mlp_kernel(const float* __restrict__ score,
                const int* __restrict__ label_idx,
                const float* __restrict__ b_start,
                const float* __restrict__ b_h0,
                const float* __restrict__ b_h1,
                const float* __restrict__ b_h2,
                const float* __restrict__ W_end,
                const float* __restrict__ b_end,
                const ushort* __restrict__ frag,
                float* __restrict__ out) {
    __shared__ ushort act[EBLK][STRIDE];
    __shared__ float pdot[3 * EBLK];
    const int tid = threadIdx.x;
    const int lane = tid & 63;
    const int wave = tid >> 6;

    // zero the K-pad region (feats 144..159); layers write only 0..143, so it stays zero
    for (int i = tid; i < EBLK * 16; i += NTHREADS)
        act[i >> 4][144 + (i & 15)] = 0;

    // gather: act[e][j] = bf16(score[label_idx[e][j]]), int4-vectorized index loads
    const int4* lidx4 = (const int4*)label_idx;
    const long base4 = (long)blockIdx.x * 512;   // 64 edges * 32 idx / 4
    for (int i = tid; i < 512; i += NTHREADS) {
        int4 v = lidx4[base4 + i];
        float f0 = score[v.x], f1 = score[v.y], f2 = score[v.z], f3 = score[v.w];
        uint2 o;
        o.x = cvt_pk_bf16(f0, f1);
        o.y = cvt_pk_bf16(f2, f3);
        *(uint2*)&act[i >> 3][(i & 7) * 4] = o;
    }
    __syncthreads();

    layer_op<1, false>(frag,                b_start, act, nullptr, nullptr, wave, lane);
    layer_op<5, false>(frag + 4608,         b_h0,    act, nullptr, nullptr, wave, lane);
    layer_op<5, false>(frag + 4608 + 23040, b_h1,    act, nullptr, nullptr, wave, lane);
    layer_op<5, true >(frag + 4608 + 46080, b_h2,    act, W_end,   pdot,    wave, lane);

    if (tid < EBLK)
        out[blockIdx.x * EBLK + tid] =
            b_end[0] + pdot[tid] + pdot[EBLK + tid] + pdot[2 * EBLK + tid];
}

extern "C" void kernel_launch(void* const* d_in, const int* in_sizes, int n_in,
                              void* d_out, int out_size, void* d_ws, size_t ws_size,
                              hipStream_t stream) {
    const float* score   = (const float*)d_in[0];
    const int*   lidx    = (const int*)  d_in[1];
    const float* W_start = (const float*)d_in[2];
    const float* b_start = (const float*)d_in[3];
    const float* W_h0    = (const float*)d_in[4];
    const float* b_h0    = (const float*)d_in[5];
    const float* W_h1    = (const float*)d_in[6];
    const float* b_h1    = (const float*)d_in[7];
    const float* W_h2    = (const float*)d_in[8];
    const float* b_h2    = (const float*)d_in[9];
    const float* W_end   = (const float*)d_in[10];
    const float* b_end   = (const float*)d_in[11];
    float* out = (float*)d_out;

    ushort* frag = (ushort*)d_ws;   // 73728 bf16 = 147456 B of repacked weights

    const int n_edges = in_sizes[1] / 32;   // label_idx is [E][32]; in_sizes is FLAT element count

    repack_kernel<<<288, 256, 0, stream>>>(W_start, W_h0, W_h1, W_h2, frag);

    mlp_kernel<<<n_edges / EBLK, NTHREADS, 0, stream>>>(score, lidx, b_start, b_h0, b_h1, b_h2,
                                                        W_end, b_end, frag, out);
}

// Round 4
// 275.168 us; speedup vs baseline: 1.3147x; 1.1845x over previous
//
#include <hip/hip_runtime.h>

#define EPW 32       // edges per wave (wave-autonomous tile)
#define NTH 128      // 2 waves per block
#define STRIDE 168   // padded feature stride in bf16 (row = 336 B, 16B-aligned; er vs er+8 = 2-way bank alias = free)

using f32x4 = __attribute__((ext_vector_type(4))) float;
using bf8   = __attribute__((ext_vector_type(8))) short;

__device__ __forceinline__ ushort f2bf(float f) {
    union { float f; unsigned u; } c{f};
    unsigned u = c.u;
    return (ushort)((u + 0x7fffu + ((u >> 16) & 1u)) >> 16);   // RTNE
}

__device__ __forceinline__ unsigned cvt_pk_bf16(float lo, float hi) {
    unsigned r;
    asm("v_cvt_pk_bf16_f32 %0, %1, %2" : "=v"(r) : "v"(lo), "v"(hi));
    return r;
}

// ---------------- weight repack: f32 [K][N] -> bf16 A-fragment lines ----------------
// A-frag (mfma_f32_16x16x32_bf16): lane l holds A[m=l&15][k=(l>>4)*8+j], j=0..7
// frag[((nt*KS+ks)*64+l)*8+j]; m = nt*16+(l&15); k = ks*32+(l>>4)*8+j
__global__ void repack_kernel(const float* __restrict__ Wstart,
                              const float* __restrict__ Wh0,
                              const float* __restrict__ Wh1,
                              const float* __restrict__ Wh2,
                              ushort* __restrict__ frag) {
    int i = blockIdx.x * blockDim.x + threadIdx.x;
    if (i < 4608) {                       // start: 9 nt * 1 ks * 64 * 8
        int j = i & 7, l = (i >> 3) & 63, nt = i >> 9;
        int k = ((l >> 4) << 3) + j;
        int n = nt * 16 + (l & 15);
        frag[i] = f2bf(Wstart[k * 144 + n]);
    } else if (i < 73728) {               // hidden: 3 * (9 nt * 5 ks * 64 * 8)
        int r = i - 4608;
        int h = r / 23040; r %= 23040;
        const float* W = (h == 0) ? Wh0 : ((h == 1) ? Wh1 : Wh2);
        int j = r & 7, l = (r >> 3) & 63, rem = r >> 9;
        int ks = rem % 5, nt = rem / 5;
        int k = ks * 32 + ((l >> 4) << 3) + j;
        int n = nt * 16 + (l & 15);
        float v = (k < 144) ? W[k * 144 + n] : 0.0f;
        frag[i] = f2bf(v);
    }
}

// ---------- per-wave fused layer, in-place, no barriers ----------
// act is this wave's private [32][STRIDE] slice. Reads all B-fragments into regs
// (program order + per-wave LDS FIFO => safe vs the in-place writes below).
// C layout: col (l&15)=edge-in-16, row ((l>>4)*4+r)=out-feature [HW-verified].
template<int KS, bool FINAL>
__device__ __forceinline__ void layer_w(const ushort* __restrict__ wfrag,
                                        const float* __restrict__ bias,
                                        ushort (*act)[STRIDE],
                                        const float* __restrict__ W_end,
                                        float* part, int lane) {
    const int grp = lane >> 4, er = lane & 15;
    bf8 xf[2][KS];
    #pragma unroll
    for (int t = 0; t < 2; t++)
        #pragma unroll
        for (int k = 0; k < KS; k++)
            xf[t][k] = *(const bf8*)&act[t * 16 + er][k * 32 + grp * 8];

    #pragma unroll
    for (int nt = 0; nt < 9; nt++) {
        f32x4 bv;
        {
            float4 b4 = *(const float4*)&bias[nt * 16 + grp * 4];
            bv[0] = b4.x; bv[1] = b4.y; bv[2] = b4.z; bv[3] = b4.w;
        }
        f32x4 acc0 = bv, acc1 = bv;
        #pragma unroll
        for (int k = 0; k < KS; k++) {
            bf8 wf = *(const bf8*)&wfrag[(((nt * KS + k) << 6) + lane) << 3];
            acc0 = __builtin_amdgcn_mfma_f32_16x16x32_bf16(wf, xf[0][k], acc0, 0, 0, 0);
            acc1 = __builtin_amdgcn_mfma_f32_16x16x32_bf16(wf, xf[1][k], acc1, 0, 0, 0);
        }
        if constexpr (FINAL) {
            // fold x @ W_end into the epilogue, f32, no bf16 round-trip
            float4 wv = *(const float4*)&W_end[nt * 16 + grp * 4];
            part[0] += fmaxf(acc0[0], 0.f) * wv.x + fmaxf(acc0[1], 0.f) * wv.y
                     + fmaxf(acc0[2], 0.f) * wv.z + fmaxf(acc0[3], 0.f) * wv.w;
            part[1] += fmaxf(acc1[0], 0.f) * wv.x + fmaxf(acc1[1], 0.f) * wv.y
                     + fmaxf(acc1[2], 0.f) * wv.z + fmaxf(acc1[3], 0.f) * wv.w;
        } else {
            uint2 o0, o1;
            o0.x = cvt_pk_bf16(fmaxf(acc0[0], 0.f), fmaxf(acc0[1], 0.f));
            o0.y = cvt_pk_bf16(fmaxf(acc0[2], 0.f), fmaxf(acc0[3], 0.f));
            o1.x = cvt_pk_bf16(fmaxf(acc1[0], 0.f), fmaxf(acc1[1], 0.f));
            o1.y = cvt_pk_bf16(fmaxf(acc1[2], 0.f), fmaxf(acc1[3], 0.f));
            *(uint2*)&act[er][nt * 16 + grp * 4]      = o0;
            *(uint2*)&act[16 + er][nt * 16 + grp * 4] = o1;
        }
    }
}

__global__ __launch_bounds__(NTH, 4)
void mlp_kernel(const float* __restrict__ score,
                const int* __restrict__ label_idx,
                const float* __restrict__ b_start,
                const float* __restrict__ b_h0,
                const float* __restrict__ b_h1,
                const float* __restrict__ b_h2,
                const float* __restrict__ W_end,
                const float* __restrict__ b_end,
                const ushort* __restrict__ frag,
                float* __restrict__ out) {
    __shared__ ushort act_s[2 * EPW][STRIDE];
    const int tid = threadIdx.x;
    const int lane = tid & 63;
    const int wave = tid >> 6;
    ushort (*act)[STRIDE] = &act_s[wave * EPW];
    const long gid = (long)blockIdx.x * 2 + wave;   // global wave id = edge-tile id

    // zero K-pad cols 144..159 (one b128 per lane; layers never write cols >=144)
    {
        uint4 z = {0u, 0u, 0u, 0u};
        *(uint4*)&act[lane & 31][144 + ((lane >> 5) << 3)] = z;
    }

    // gather: 32 edges x 32 idx = 256 int4 loads spread over 64 lanes
    const int4* lidx4 = (const int4*)label_idx + gid * 256;
    #pragma unroll
    for (int q = 0; q < 4; q++) {
        int p = q * 64 + lane;
        int4 v = lidx4[p];
        float f0 = score[v.x], f1 = score[v.y], f2 = score[v.z], f3 = score[v.w];
        uint2 o;
        o.x = cvt_pk_bf16(f0, f1);
        o.y = cvt_pk_bf16(f2, f3);
        *(uint2*)&act[p >> 3][(p & 7) << 2] = o;
    }

    // 4 fused layers, all in-place in this wave's LDS slice — no __syncthreads anywhere
    float part[2] = {0.f, 0.f};
    layer_w<1, false>(frag,                 b_start, act, nullptr, part, lane);
    layer_w<5, false>(frag + 4608,          b_h0,    act, nullptr, part, lane);
    layer_w<5, false>(frag + 4608 + 23040,  b_h1,    act, nullptr, part, lane);
    layer_w<5, true >(frag + 4608 + 46080,  b_h2,    act, W_end,   part, lane);

    // reduce the W_end partial dot across the 4 lane-groups
    part[0] += __shfl_xor(part[0], 16, 64);
    part[0] += __shfl_xor(part[0], 32, 64);
    part[1] += __shfl_xor(part[1], 16, 64);
    part[1] += __shfl_xor(part[1], 32, 64);
    if (lane < 16) {
        float be = b_end[0];
        out[gid * EPW + lane]      = be + part[0];
        out[gid * EPW + 16 + lane] = be + part[1];
    }
}

extern "C" void kernel_launch(void* const* d_in, const int* in_sizes, int n_in,
                              void* d_out, int out_size, void* d_ws, size_t ws_size,
                              hipStream_t stream) {
    const float* score   = (const float*)d_in[0];
    const int*   lidx    = (const int*)  d_in[1];
    const float* W_start = (const float*)d_in[2];
    const float* b_start = (const float*)d_in[3];
    const float* W_h0    = (const float*)d_in[4];
    const float* b_h0    = (const float*)d_in[5];
    const float* W_h1    = (const float*)d_in[6];
    const float* b_h1    = (const float*)d_in[7];
    const float* W_h2    = (const float*)d_in[8];
    const float* b_h2    = (const float*)d_in[9];
    const float* W_end   = (const float*)d_in[10];
    const float* b_end   = (const float*)d_in[11];
    float* out = (float*)d_out;

    ushort* frag = (ushort*)d_ws;   // 73728 bf16 = 147456 B of repacked weights

    const int n_edges = in_sizes[1] / 32;   // label_idx is [E][32]; in_sizes is FLAT count

    repack_kernel<<<288, 256, 0, stream>>>(W_start, W_h0, W_h1, W_h2, frag);

    mlp_kernel<<<n_edges / (2 * EPW), NTH, 0, stream>>>(score, lidx, b_start, b_h0, b_h1, b_h2,
                                                        W_end, b_end, frag, out);
}

// Round 5
// 218.501 us; speedup vs baseline: 1.6557x; 1.2593x over previous
//
#include <hip/hip_runtime.h>

#define EPW 64       // edges per wave (wave-autonomous tile)
#define NTH 64       // 1 wave per block
#define STRIDE 168   // padded feature stride in bf16 (row = 336 B; 336%128=80 -> b128 reads spread over 16 chunk slots)

using f32x4 = __attribute__((ext_vector_type(4))) float;
using bf8   = __attribute__((ext_vector_type(8))) short;

__device__ __forceinline__ ushort f2bf(float f) {
    union { float f; unsigned u; } c{f};
    unsigned u = c.u;
    return (ushort)((u + 0x7fffu + ((u >> 16) & 1u)) >> 16);   // RTNE
}

__device__ __forceinline__ unsigned cvt_pk_bf16(float lo, float hi) {
    unsigned r;
    asm("v_cvt_pk_bf16_f32 %0, %1, %2" : "=v"(r) : "v"(lo), "v"(hi));
    return r;
}

// ---------------- weight repack: f32 [K][N] -> bf16 A-fragment lines ----------------
// A-frag (mfma_f32_16x16x32_bf16): lane l holds A[m=l&15][k=(l>>4)*8+j], j=0..7
// frag[((nt*KS+ks)*64+l)*8+j]; m = nt*16+(l&15); k = ks*32+(l>>4)*8+j
__global__ void repack_kernel(const float* __restrict__ Wstart,
                              const float* __restrict__ Wh0,
                              const float* __restrict__ Wh1,
                              const float* __restrict__ Wh2,
                              ushort* __restrict__ frag) {
    int i = blockIdx.x * blockDim.x + threadIdx.x;
    if (i < 4608) {                       // start: 9 nt * 1 ks * 64 * 8
        int j = i & 7, l = (i >> 3) & 63, nt = i >> 9;
        int k = ((l >> 4) << 3) + j;
        int n = nt * 16 + (l & 15);
        frag[i] = f2bf(Wstart[k * 144 + n]);
    } else if (i < 73728) {               // hidden: 3 * (9 nt * 5 ks * 64 * 8)
        int r = i - 4608;
        int h = r / 23040; r %= 23040;
        const float* W = (h == 0) ? Wh0 : ((h == 1) ? Wh1 : Wh2);
        int j = r & 7, l = (r >> 3) & 63, rem = r >> 9;
        int ks = rem % 5, nt = rem / 5;
        int k = ks * 32 + ((l >> 4) << 3) + j;
        int n = nt * 16 + (l & 15);
        float v = (k < 144) ? W[k * 144 + n] : 0.0f;
        frag[i] = f2bf(v);
    }
}

// ---------- per-wave fused layer, in-place, no barriers ----------
// act = this wave's [64][STRIDE] tile. All B-fragment reads precede the in-place
// writes in wave program order (per-wave LDS ordering => safe; verified R3/R4).
// C layout: col (l&15)=edge-in-16, row ((l>>4)*4+r)=out-feature [HW-verified].
// Explicit next-nt weight prefetch (wc/wn) overlaps L2 latency with 20 MFMAs.
template<int KS, bool FINAL>
__device__ __forceinline__ void layer_w(const ushort* __restrict__ wfrag,
                                        const float* __restrict__ bias,
                                        ushort (*act)[STRIDE],
                                        const float* __restrict__ W_end,
                                        float* part, int lane) {
    const int grp = lane >> 4, er = lane & 15;
    bf8 xf[4][KS];
    #pragma unroll
    for (int t = 0; t < 4; t++)
        #pragma unroll
        for (int k = 0; k < KS; k++)
            xf[t][k] = *(const bf8*)&act[t * 16 + er][k * 32 + grp * 8];

    bf8 wc[KS], wn[KS];
    #pragma unroll
    for (int k = 0; k < KS; k++)
        wc[k] = *(const bf8*)&wfrag[((k << 6) + lane) << 3];

    #pragma unroll
    for (int nt = 0; nt < 9; nt++) {
        if (nt < 8) {
            #pragma unroll
            for (int k = 0; k < KS; k++)
                wn[k] = *(const bf8*)&wfrag[((((nt + 1) * KS + k) << 6) + lane) << 3];
        }
        f32x4 bv;
        {
            float4 b4 = *(const float4*)&bias[nt * 16 + grp * 4];
            bv[0] = b4.x; bv[1] = b4.y; bv[2] = b4.z; bv[3] = b4.w;
        }
        f32x4 acc[4] = {bv, bv, bv, bv};
        #pragma unroll
        for (int k = 0; k < KS; k++)
            #pragma unroll
            for (int t = 0; t < 4; t++)
                acc[t] = __builtin_amdgcn_mfma_f32_16x16x32_bf16(wc[k], xf[t][k], acc[t], 0, 0, 0);

        if constexpr (FINAL) {
            // fold x @ W_end into the epilogue, f32, no bf16 round-trip
            float4 wv = *(const float4*)&W_end[nt * 16 + grp * 4];
            #pragma unroll
            for (int t = 0; t < 4; t++)
                part[t] += fmaxf(acc[t][0], 0.f) * wv.x + fmaxf(acc[t][1], 0.f) * wv.y
                         + fmaxf(acc[t][2], 0.f) * wv.z + fmaxf(acc[t][3], 0.f) * wv.w;
        } else {
            #pragma unroll
            for (int t = 0; t < 4; t++) {
                uint2 o;
                o.x = cvt_pk_bf16(fmaxf(acc[t][0], 0.f), fmaxf(acc[t][1], 0.f));
                o.y = cvt_pk_bf16(fmaxf(acc[t][2], 0.f), fmaxf(acc[t][3], 0.f));
                *(uint2*)&act[t * 16 + er][nt * 16 + grp * 4] = o;
            }
        }
        #pragma unroll
        for (int k = 0; k < KS; k++)
            wc[k] = wn[k];
    }
}

__global__ __launch_bounds__(NTH, 2)
void mlp_kernel(const float* __restrict__ score,
                const int* __restrict__ label_idx,
                const float* __restrict__ b_start,
                const float* __restrict__ b_h0,
                const float* __restrict__ b_h1,
                const float* __restrict__ b_h2,
                const float* __restrict__ W_end,
                const float* __restrict__ b_end,
                const ushort* __restrict__ frag,
                float* __restrict__ out) {
    __shared__ ushort act[EPW][STRIDE];
    const int lane = threadIdx.x;
    const long gid = blockIdx.x;            // one wave per block = one 64-edge tile

    // zero K-pad cols 144..159 (layers never write cols >=144)
    {
        uint4 z = {0u, 0u, 0u, 0u};
        *(uint4*)&act[lane][144] = z;
        *(uint4*)&act[lane][152] = z;
    }

    // gather: 64 edges x 32 idx = 512 int4 loads spread over 64 lanes
    const int4* lidx4 = (const int4*)label_idx + gid * 512;
    #pragma unroll
    for (int q = 0; q < 8; q++) {
        int p = q * 64 + lane;
        int4 v = lidx4[p];
        float f0 = score[v.x], f1 = score[v.y], f2 = score[v.z], f3 = score[v.w];
        uint2 o;
        o.x = cvt_pk_bf16(f0, f1);
        o.y = cvt_pk_bf16(f2, f3);
        *(uint2*)&act[p >> 3][(p & 7) << 2] = o;
    }

    // 4 fused layers, in-place in this wave's LDS tile — no __syncthreads anywhere
    float part[4] = {0.f, 0.f, 0.f, 0.f};
    layer_w<1, false>(frag,                 b_start, act, nullptr, part, lane);
    layer_w<5, false>(frag + 4608,          b_h0,    act, nullptr, part, lane);
    layer_w<5, false>(frag + 4608 + 23040,  b_h1,    act, nullptr, part, lane);
    layer_w<5, true >(frag + 4608 + 46080,  b_h2,    act, W_end,   part, lane);

    // reduce the W_end partial dots across the 4 lane-groups
    #pragma unroll
    for (int t = 0; t < 4; t++) {
        part[t] += __shfl_xor(part[t], 16, 64);
        part[t] += __shfl_xor(part[t], 32, 64);
    }
    if (lane < 16) {
        float be = b_end[0];
        #pragma unroll
        for (int t = 0; t < 4; t++)
            out[gid * EPW + t * 16 + lane] = be + part[t];
    }
}

extern "C" void kernel_launch(void* const* d_in, const int* in_sizes, int n_in,
                              void* d_out, int out_size, void* d_ws, size_t ws_size,
                              hipStream_t stream) {
    const float* score   = (const float*)d_in[0];
    const int*   lidx    = (const int*)  d_in[1];
    const float* W_start = (const float*)d_in[2];
    const float* b_start = (const float*)d_in[3];
    const float* W_h0    = (const float*)d_in[4];
    const float* b_h0    = (const float*)d_in[5];
    const float* W_h1    = (const float*)d_in[6];
    const float* b_h1    = (const float*)d_in[7];
    const float* W_h2    = (const float*)d_in[8];
    const float* b_h2    = (const float*)d_in[9];
    const float* W_end   = (const float*)d_in[10];
    const float* b_end   = (const float*)d_in[11];
    float* out = (float*)d_out;

    ushort* frag = (ushort*)d_ws;   // 73728 bf16 = 147456 B of repacked weights

    const int n_edges = in_sizes[1] / 32;   // label_idx is [E][32]; in_sizes is FLAT count

    repack_kernel<<<288, 256, 0, stream>>>(W_start, W_h0, W_h1, W_h2, frag);

    mlp_kernel<<<n_edges / EPW, NTH, 0, stream>>>(score, lidx, b_start, b_h0, b_h1, b_h2,
                                                  W_end, b_end, frag, out);
}